// Round 1
// baseline (7709.756 us; speedup 1.0000x reference)
//
#include <hip/hip_runtime.h>
#include <stdint.h>

#define BB 64
#define DD 512
#define HH 1024
#define VV 32000
#define T_STEPS 50
#define G3 3072

__device__ __forceinline__ uint32_t rotl32(uint32_t x, int d) {
  return (x << d) | (x >> (32 - d));
}

// JAX threefry2x32 (20 rounds), exact rotation/key schedule.
__device__ __forceinline__ void threefry2x32(uint32_t k0, uint32_t k1,
                                             uint32_t& x0, uint32_t& x1) {
  uint32_t ks0 = k0, ks1 = k1, ks2 = k0 ^ k1 ^ 0x1BD11BDAu;
  x0 += ks0; x1 += ks1;
#define TF_R(r) { x0 += x1; x1 = rotl32(x1, (r)); x1 ^= x0; }
  TF_R(13) TF_R(15) TF_R(26) TF_R(6)
  x0 += ks1; x1 += ks2 + 1u;
  TF_R(17) TF_R(29) TF_R(16) TF_R(24)
  x0 += ks2; x1 += ks0 + 2u;
  TF_R(13) TF_R(15) TF_R(26) TF_R(6)
  x0 += ks0; x1 += ks1 + 3u;
  TF_R(17) TF_R(29) TF_R(16) TF_R(24)
  x0 += ks1; x1 += ks2 + 4u;
  TF_R(13) TF_R(15) TF_R(26) TF_R(6)
  x0 += ks2; x1 += ks0 + 5u;
#undef TF_R
}

// C[64][ldc] tile = A[64][K] @ Bw[N][K]^T (+bias), cols [n0, n0+BN)
template<int BN, int TN>
__device__ __forceinline__ void gemm_body(
    float (*__restrict__ As)[68], float (*__restrict__ Bs)[BN + 4],
    const float* __restrict__ A, const float* __restrict__ Bw,
    const float* __restrict__ bias, float* __restrict__ C,
    int K, int ldc, int n0)
{
  const int tid = threadIdx.x;
  const int tx = tid & 15, ty = tid >> 4;
  const int m0 = ty * 4, nn0 = tx * TN;

  float acc[4][TN];
#pragma unroll
  for (int i = 0; i < 4; ++i)
#pragma unroll
    for (int j = 0; j < TN; ++j) acc[i][j] = 0.f;

  const int ma = tid >> 3;         // 0..31
  const int k4 = (tid & 7) << 2;   // 0,4,..,28

  for (int k0 = 0; k0 < K; k0 += 32) {
    float4 a0 = *(const float4*)(A + (size_t)ma * K + k0 + k4);
    float4 a1 = *(const float4*)(A + (size_t)(ma + 32) * K + k0 + k4);
    As[k4 + 0][ma] = a0.x; As[k4 + 1][ma] = a0.y;
    As[k4 + 2][ma] = a0.z; As[k4 + 3][ma] = a0.w;
    As[k4 + 0][ma + 32] = a1.x; As[k4 + 1][ma + 32] = a1.y;
    As[k4 + 2][ma + 32] = a1.z; As[k4 + 3][ma + 32] = a1.w;
#pragma unroll
    for (int r = ma; r < BN; r += 32) {
      float4 bv = *(const float4*)(Bw + (size_t)(n0 + r) * K + k0 + k4);
      Bs[k4 + 0][r] = bv.x; Bs[k4 + 1][r] = bv.y;
      Bs[k4 + 2][r] = bv.z; Bs[k4 + 3][r] = bv.w;
    }
    __syncthreads();
#pragma unroll
    for (int k = 0; k < 32; ++k) {
      const float4 av = *(const float4*)&As[k][m0];
      float a[4] = {av.x, av.y, av.z, av.w};
      float b[TN];
      if constexpr (TN == 4) {
        const float4 bv = *(const float4*)&Bs[k][nn0];
        b[0] = bv.x; b[1] = bv.y; b[2] = bv.z; b[3] = bv.w;
      } else {
        const float2 bv = *(const float2*)&Bs[k][nn0];
        b[0] = bv.x; b[1] = bv.y;
      }
#pragma unroll
      for (int i = 0; i < 4; ++i)
#pragma unroll
        for (int j = 0; j < TN; ++j)
          acc[i][j] = fmaf(a[i], b[j], acc[i][j]);
    }
    __syncthreads();
  }
#pragma unroll
  for (int i = 0; i < 4; ++i)
#pragma unroll
    for (int j = 0; j < TN; ++j) {
      float v = acc[i][j];
      if (bias) v += bias[n0 + nn0 + j];
      C[(size_t)(m0 + i) * ldc + n0 + nn0 + j] = v;
    }
}

template<int BN, int TN>
__global__ __launch_bounds__(256) void gemm64(
    const float* __restrict__ A, const float* __restrict__ Bw,
    const float* __restrict__ bias, float* __restrict__ C, int K, int ldc)
{
  __shared__ float As[32][68];
  __shared__ float Bs[32][BN + 4];
  gemm_body<BN, TN>(As, Bs, A, Bw, bias, C, K, ldc, blockIdx.x * BN);
}

// blocks 0..95: gi = x @ W_ih^T ; blocks 96..191: gh = h @ W_hh^T
__global__ __launch_bounds__(256) void gates_gemm(
    const float* __restrict__ x, const float* __restrict__ Wih,
    const float* __restrict__ h, const float* __restrict__ Whh,
    float* __restrict__ gi, float* __restrict__ gh)
{
  __shared__ float As[32][68];
  __shared__ float Bs[32][36];
  if (blockIdx.x < 96)
    gemm_body<32, 2>(As, Bs, x, Wih, nullptr, gi, DD, G3, blockIdx.x * 32);
  else
    gemm_body<32, 2>(As, Bs, h, Whh, nullptr, gh, HH, G3, (blockIdx.x - 96) * 32);
}

__global__ __launch_bounds__(256) void gru_gate(
    const float* __restrict__ gi, const float* __restrict__ gh,
    const float* __restrict__ bih, const float* __restrict__ bhh,
    float* __restrict__ h)
{
  int i = blockIdx.x * 256 + threadIdx.x;      // 0..65535
  int b = i >> 10, j = i & 1023;
  const float* gib = gi + (size_t)b * G3;
  const float* ghb = gh + (size_t)b * G3;
  float ir = gib[j]        + bih[j],        hr = ghb[j]        + bhh[j];
  float iz = gib[j + 1024] + bih[j + 1024], hz = ghb[j + 1024] + bhh[j + 1024];
  float in_ = gib[j + 2048] + bih[j + 2048], hn = ghb[j + 2048] + bhh[j + 2048];
  float r = 1.f / (1.f + expf(-(ir + hr)));
  float z = 1.f / (1.f + expf(-(iz + hz)));
  float n = tanhf(in_ + r * hn);
  float hv = h[i];
  h[i] = (1.f - z) * n + z * hv;
}

// one block per batch row: gumbel-argmax sample + embedding gather
__global__ __launch_bounds__(1024) void sample_kernel(
    const float* __restrict__ logits, const float* __restrict__ emb,
    float* __restrict__ x, float* __restrict__ idx_out, int t)
{
  __shared__ float sv[1024];
  __shared__ int si[1024];
  __shared__ int s_best;
  const int b = blockIdx.x, tid = threadIdx.x;

  // key_t = threefry((0,42),(0,t))  [partitionable fold-like split]
  uint32_t kt0 = 0u, kt1 = (uint32_t)t;
  threefry2x32(0u, 42u, kt0, kt1);

  const float* lrow = logits + (size_t)b * VV;
  float best = -INFINITY; int bidx = 0;
  for (int v = tid; v < VV; v += 1024) {
    uint32_t c0 = 0u, c1 = (uint32_t)(b * VV + v);
    threefry2x32(kt0, kt1, c0, c1);
    uint32_t bits = c0 ^ c1;                       // 32-bit XOR fold
    float u = __uint_as_float((bits >> 9) | 0x3f800000u) - 1.0f;
    if (u == 0.0f) u = 1.17549435e-38f;            // minval = tiny
    float g = -logf(-logf(u));
    float val = g + lrow[v];
    if (val > best) { best = val; bidx = v; }      // strict >: first max wins
  }
  sv[tid] = best; si[tid] = bidx;
  __syncthreads();
  for (int s = 512; s > 0; s >>= 1) {
    if (tid < s) {
      float v2 = sv[tid + s]; int i2 = si[tid + s];
      if (v2 > sv[tid] || (v2 == sv[tid] && i2 < si[tid])) { sv[tid] = v2; si[tid] = i2; }
    }
    __syncthreads();
  }
  if (tid == 0) { s_best = si[0]; idx_out[b] = (float)si[0]; }
  __syncthreads();
  const int ebase = s_best * DD;
  if (tid < DD) x[(size_t)b * DD + tid] = emb[ebase + tid];
}

__global__ __launch_bounds__(256) void init_kernel(
    const float* __restrict__ seq, const float* __restrict__ emb,
    const int* __restrict__ eos, float* __restrict__ h, float* __restrict__ x)
{
  int i = blockIdx.x * 256 + threadIdx.x;
  if (i < BB * HH) h[i] = seq[i];
  if (i < BB * DD) x[i] = emb[(size_t)eos[0] * DD + (i & (DD - 1))];
}

extern "C" void kernel_launch(void* const* d_in, const int* in_sizes, int n_in,
                              void* d_out, int out_size, void* d_ws, size_t ws_size,
                              hipStream_t stream) {
  const float* seq = (const float*)d_in[0];
  const float* emb = (const float*)d_in[1];
  const float* Wih = (const float*)d_in[2];
  const float* Whh = (const float*)d_in[3];
  const float* bih = (const float*)d_in[4];
  const float* bhh = (const float*)d_in[5];
  const float* fcw = (const float*)d_in[6];
  const float* fcb = (const float*)d_in[7];
  const int*   eos = (const int*)d_in[8];

  float* out = (float*)d_out;
  float* idx_out = out;                              // [50][64] as float
  float* log_out = out + (size_t)T_STEPS * BB;       // [50][64][32000]

  float* ws = (float*)d_ws;
  float* x  = ws;                    // [64][512]
  float* h  = ws + BB * DD;          // [64][1024]
  float* gi = h + BB * HH;           // [64][3072]
  float* gh = gi + BB * G3;          // [64][3072]

  init_kernel<<<256, 256, 0, stream>>>(seq, emb, eos, h, x);

  for (int t = 0; t < T_STEPS; ++t) {
    float* lg = log_out + (size_t)t * BB * VV;
    gates_gemm<<<192, 256, 0, stream>>>(x, Wih, h, Whh, gi, gh);
    gru_gate<<<(BB * HH) / 256, 256, 0, stream>>>(gi, gh, bih, bhh, h);
    gemm64<64, 4><<<VV / 64, 256, 0, stream>>>(h, fcw, fcb, lg, HH, VV);
    sample_kernel<<<BB, 1024, 0, stream>>>(lg, emb, x, idx_out + t * BB, t);
  }
}

// Round 2
// 3829.748 us; speedup vs baseline: 2.0131x; 2.0131x over previous
//
#include <hip/hip_runtime.h>
#include <stdint.h>

#define BB 64
#define DD 512
#define HH 1024
#define VV 32000
#define T_STEPS 50
#define G3 3072
#define NBLK_LOG (VV / 64)   // 500

typedef __attribute__((ext_vector_type(8))) short bf16x8;
typedef __attribute__((ext_vector_type(4))) float f32x4;
typedef unsigned long long u64;
typedef unsigned short ushort_t;

__device__ __forceinline__ uint32_t rotl32(uint32_t x, int d) {
  return (x << d) | (x >> (32 - d));
}

// JAX threefry2x32 (20 rounds) — verified exact in round 1.
__device__ __forceinline__ void threefry2x32(uint32_t k0, uint32_t k1,
                                             uint32_t& x0, uint32_t& x1) {
  uint32_t ks0 = k0, ks1 = k1, ks2 = k0 ^ k1 ^ 0x1BD11BDAu;
  x0 += ks0; x1 += ks1;
#define TF_R(r) { x0 += x1; x1 = rotl32(x1, (r)); x1 ^= x0; }
  TF_R(13) TF_R(15) TF_R(26) TF_R(6)
  x0 += ks1; x1 += ks2 + 1u;
  TF_R(17) TF_R(29) TF_R(16) TF_R(24)
  x0 += ks2; x1 += ks0 + 2u;
  TF_R(13) TF_R(15) TF_R(26) TF_R(6)
  x0 += ks0; x1 += ks1 + 3u;
  TF_R(17) TF_R(29) TF_R(16) TF_R(24)
  x0 += ks1; x1 += ks2 + 4u;
  TF_R(13) TF_R(15) TF_R(26) TF_R(6)
  x0 += ks2; x1 += ks0 + 5u;
#undef TF_R
}

// fp32 -> bf16 bits (RTN-even)
__device__ __forceinline__ uint32_t f2bf(float f) {
  uint32_t u = __float_as_uint(f);
  return (u + 0x7fffu + ((u >> 16) & 1u)) >> 16;
}
__device__ __forceinline__ float bf2f(uint32_t b) { return __uint_as_float(b << 16); }

// monotonic (val, idx) packing: larger val wins; ties -> smaller idx wins
__device__ __forceinline__ u64 packkey(float v, int c) {
  uint32_t s = __float_as_uint(v);
  uint32_t mo = (s & 0x80000000u) ? ~s : (s | 0x80000000u);
  return ((u64)mo << 32) | (uint32_t)(~(uint32_t)c);
}
__device__ __forceinline__ u64 umax64(u64 a, u64 b) { return a > b ? a : b; }

// C[64][ldc] tile (cols n0..n0+63) = A @ B^T, A = Ahi+Alo bf16 [64][K],
// B = fp32 [N][K] split to bf16 hi/lo in LDS. 256 threads = 4 waves in 2x2
// quadrant grid. EPI=0: plain fp32 store. EPI=1: store + fused gumbel-argmax
// partial per row -> partial[row*nblk + bid].
template<int EPI>
__device__ __forceinline__ void mfma_body(
    ushort_t (*__restrict__ bhS)[40], ushort_t (*__restrict__ blS)[40],
    u64 (*__restrict__ scr)[2],
    const ushort_t* __restrict__ Ahi, const ushort_t* __restrict__ Alo,
    const float* __restrict__ Bw, int K,
    const float* __restrict__ bias,
    float* __restrict__ C, int ldc, int n0,
    u64* __restrict__ partial, int nblk, int bid, int t)
{
  const int tid = threadIdx.x;
  const int lane = tid & 63, w = tid >> 6;
  const int l15 = lane & 15, q = lane >> 4;
  const int rw = (w >> 1) * 32, cw = (w & 1) * 32;

  f32x4 acc[2][2] = {};

  const int srow = tid >> 2;             // 0..63  (B-tile row = output col)
  const int schunk = (tid & 3) * 8;      // 0,8,16,24

  for (int k0 = 0; k0 < K; k0 += 32) {
    // ---- global loads (B fp32 staging chunk + A bf16 fragments) ----
    const float* bp = Bw + (size_t)(n0 + srow) * K + k0 + schunk;
    float4 v0 = *(const float4*)bp;
    float4 v1 = *(const float4*)(bp + 4);

    bf16x8 ah[2], al[2];
#pragma unroll
    for (int m = 0; m < 2; ++m) {
      const size_t ao = (size_t)(rw + 16 * m + l15) * K + k0 + 8 * q;
      ah[m] = *(const bf16x8*)(Ahi + ao);
      al[m] = *(const bf16x8*)(Alo + ao);
    }

    __syncthreads();   // previous read phase done before overwrite
    {
      float f[8] = {v0.x, v0.y, v0.z, v0.w, v1.x, v1.y, v1.z, v1.w};
      uint32_t ph[4], pl[4];
#pragma unroll
      for (int i = 0; i < 4; ++i) {
        float a = f[2 * i], b = f[2 * i + 1];
        uint32_t ha = f2bf(a), hb = f2bf(b);
        float ra = a - bf2f(ha), rb = b - bf2f(hb);
        ph[i] = ha | (hb << 16);
        pl[i] = f2bf(ra) | (f2bf(rb) << 16);
      }
      *(uint4*)&bhS[srow][schunk] = make_uint4(ph[0], ph[1], ph[2], ph[3]);
      *(uint4*)&blS[srow][schunk] = make_uint4(pl[0], pl[1], pl[2], pl[3]);
    }
    __syncthreads();

    bf16x8 bhf[2], blf[2];
#pragma unroll
    for (int n = 0; n < 2; ++n) {
      bhf[n] = *(const bf16x8*)&bhS[cw + 16 * n + l15][8 * q];
      blf[n] = *(const bf16x8*)&blS[cw + 16 * n + l15][8 * q];
    }
#pragma unroll
    for (int m = 0; m < 2; ++m)
#pragma unroll
      for (int n = 0; n < 2; ++n) {
        acc[m][n] = __builtin_amdgcn_mfma_f32_16x16x32_bf16(ah[m], bhf[n], acc[m][n], 0, 0, 0);
        acc[m][n] = __builtin_amdgcn_mfma_f32_16x16x32_bf16(ah[m], blf[n], acc[m][n], 0, 0, 0);
        acc[m][n] = __builtin_amdgcn_mfma_f32_16x16x32_bf16(al[m], bhf[n], acc[m][n], 0, 0, 0);
      }
  }

  if constexpr (EPI == 0) {
#pragma unroll
    for (int m = 0; m < 2; ++m)
#pragma unroll
      for (int n = 0; n < 2; ++n)
#pragma unroll
        for (int r = 0; r < 4; ++r) {
          int row = rw + 16 * m + 4 * q + r;
          int col = n0 + cw + 16 * n + l15;
          C[(size_t)row * ldc + col] = acc[m][n][r];
        }
  } else {
    // per-step sampling key (uniform across lanes)
    uint32_t kt0 = 0u, kt1 = (uint32_t)t;
    threefry2x32(0u, 42u, kt0, kt1);

    u64 bk[2][4];
#pragma unroll
    for (int m = 0; m < 2; ++m)
#pragma unroll
      for (int r = 0; r < 4; ++r) bk[m][r] = 0ull;

#pragma unroll
    for (int m = 0; m < 2; ++m)
#pragma unroll
      for (int n = 0; n < 2; ++n)
#pragma unroll
        for (int r = 0; r < 4; ++r) {
          int row = rw + 16 * m + 4 * q + r;          // batch index
          int col = n0 + cw + 16 * n + l15;           // vocab index
          float val = acc[m][n][r] + bias[col];
          C[(size_t)row * ldc + col] = val;
          uint32_t c0 = 0u, c1 = (uint32_t)(row * VV + col);
          threefry2x32(kt0, kt1, c0, c1);
          uint32_t bits = c0 ^ c1;
          float u = __uint_as_float((bits >> 9) | 0x3f800000u) - 1.0f;
          if (u == 0.0f) u = 1.17549435e-38f;
          float g = -__logf(-__logf(u));
          bk[m][r] = umax64(bk[m][r], packkey(val + g, col));
        }
    // reduce over the 16 lanes of each q-group (cols of this wave)
#pragma unroll
    for (int off = 1; off < 16; off <<= 1)
#pragma unroll
      for (int m = 0; m < 2; ++m)
#pragma unroll
        for (int r = 0; r < 4; ++r)
          bk[m][r] = umax64(bk[m][r], (u64)__shfl_xor((long long)bk[m][r], off, 64));

    if (l15 == 0) {
#pragma unroll
      for (int m = 0; m < 2; ++m)
#pragma unroll
        for (int r = 0; r < 4; ++r)
          scr[rw + 16 * m + 4 * q + r][w & 1] = bk[m][r];
    }
    __syncthreads();
    if (tid < 64) {
      u64 fk = umax64(scr[tid][0], scr[tid][1]);
      partial[(size_t)tid * nblk + bid] = fk;
    }
  }
}

__global__ __launch_bounds__(256) void gates_mfma(
    const ushort_t* __restrict__ xh, const ushort_t* __restrict__ xl,
    const float* __restrict__ Wih,
    const ushort_t* __restrict__ hh, const ushort_t* __restrict__ hl,
    const float* __restrict__ Whh,
    float* __restrict__ gi, float* __restrict__ gh)
{
  __shared__ ushort_t bhS[64][40];
  __shared__ ushort_t blS[64][40];
  __shared__ u64 scr[64][2];
  if (blockIdx.x < G3 / 64)
    mfma_body<0>(bhS, blS, scr, xh, xl, Wih, DD, nullptr, gi, G3,
                 blockIdx.x * 64, nullptr, 0, 0, 0);
  else
    mfma_body<0>(bhS, blS, scr, hh, hl, Whh, HH, nullptr, gh, G3,
                 (blockIdx.x - G3 / 64) * 64, nullptr, 0, 0, 0);
}

__global__ __launch_bounds__(256) void logits_mfma(
    const ushort_t* __restrict__ hh, const ushort_t* __restrict__ hl,
    const float* __restrict__ fcw, const float* __restrict__ fcb,
    float* __restrict__ lg, u64* __restrict__ partial, int t)
{
  __shared__ ushort_t bhS[64][40];
  __shared__ ushort_t blS[64][40];
  __shared__ u64 scr[64][2];
  mfma_body<1>(bhS, blS, scr, hh, hl, fcw, HH, fcb, lg, VV,
               blockIdx.x * 64, partial, NBLK_LOG, blockIdx.x, t);
}

__global__ __launch_bounds__(256) void gru_gate(
    const float* __restrict__ gi, const float* __restrict__ gh,
    const float* __restrict__ bih, const float* __restrict__ bhh,
    float* __restrict__ h, ushort_t* __restrict__ hhi, ushort_t* __restrict__ hlo)
{
  int i = blockIdx.x * 256 + threadIdx.x;      // 0..65535
  int b = i >> 10, j = i & 1023;
  const float* gib = gi + (size_t)b * G3;
  const float* ghb = gh + (size_t)b * G3;
  float ir = gib[j]        + bih[j],        hr = ghb[j]        + bhh[j];
  float iz = gib[j + 1024] + bih[j + 1024], hz = ghb[j + 1024] + bhh[j + 1024];
  float in_ = gib[j + 2048] + bih[j + 2048], hn = ghb[j + 2048] + bhh[j + 2048];
  float r = 1.f / (1.f + expf(-(ir + hr)));
  float z = 1.f / (1.f + expf(-(iz + hz)));
  float n = tanhf(in_ + r * hn);
  float hv = (1.f - z) * n + z * h[i];
  h[i] = hv;
  uint32_t hb = f2bf(hv);
  hhi[i] = (ushort_t)hb;
  hlo[i] = (ushort_t)f2bf(hv - bf2f(hb));
}

__global__ __launch_bounds__(256) void finish_sample(
    const u64* __restrict__ partial, const float* __restrict__ emb,
    float* __restrict__ idx_out, ushort_t* __restrict__ xh, ushort_t* __restrict__ xl)
{
  __shared__ u64 red[256];
  __shared__ int sidx;
  const int b = blockIdx.x, tid = threadIdx.x;
  u64 best = 0;
  for (int i = tid; i < NBLK_LOG; i += 256) {
    u64 v = partial[(size_t)b * NBLK_LOG + i];
    if (v > best) best = v;
  }
  red[tid] = best;
  __syncthreads();
  for (int s = 128; s > 0; s >>= 1) {
    if (tid < s) { if (red[tid + s] > red[tid]) red[tid] = red[tid + s]; }
    __syncthreads();
  }
  if (tid == 0) {
    int idx = (int)(~(uint32_t)red[0]);
    sidx = idx;
    idx_out[b] = (float)idx;
  }
  __syncthreads();
  const float2* ep = (const float2*)(emb + (size_t)sidx * DD);
  float2 v = ep[tid];
  uint32_t h0 = f2bf(v.x), h1 = f2bf(v.y);
  uint32_t l0 = f2bf(v.x - bf2f(h0)), l1 = f2bf(v.y - bf2f(h1));
  *(uint32_t*)&xh[(size_t)b * DD + 2 * tid] = h0 | (h1 << 16);
  *(uint32_t*)&xl[(size_t)b * DD + 2 * tid] = l0 | (l1 << 16);
}

__global__ __launch_bounds__(256) void init_kernel(
    const float* __restrict__ seq, const float* __restrict__ emb,
    const int* __restrict__ eos, float* __restrict__ h,
    ushort_t* __restrict__ hhi, ushort_t* __restrict__ hlo,
    ushort_t* __restrict__ xh, ushort_t* __restrict__ xl)
{
  int i = blockIdx.x * 256 + threadIdx.x;
  if (i < BB * HH) {
    float v = seq[i];
    h[i] = v;
    uint32_t hb = f2bf(v);
    hhi[i] = (ushort_t)hb;
    hlo[i] = (ushort_t)f2bf(v - bf2f(hb));
  }
  if (i < BB * DD) {
    float v = emb[(size_t)eos[0] * DD + (i & (DD - 1))];
    uint32_t hb = f2bf(v);
    xh[i] = (ushort_t)hb;
    xl[i] = (ushort_t)f2bf(v - bf2f(hb));
  }
}

extern "C" void kernel_launch(void* const* d_in, const int* in_sizes, int n_in,
                              void* d_out, int out_size, void* d_ws, size_t ws_size,
                              hipStream_t stream) {
  const float* seq = (const float*)d_in[0];
  const float* emb = (const float*)d_in[1];
  const float* Wih = (const float*)d_in[2];
  const float* Whh = (const float*)d_in[3];
  const float* bih = (const float*)d_in[4];
  const float* bhh = (const float*)d_in[5];
  const float* fcw = (const float*)d_in[6];
  const float* fcb = (const float*)d_in[7];
  const int*   eos = (const int*)d_in[8];

  float* out = (float*)d_out;
  float* idx_out = out;                              // [50][64] as float
  float* log_out = out + (size_t)T_STEPS * BB;       // [50][64][32000]

  uint8_t* wsp = (uint8_t*)d_ws;
  auto alloc = [&](size_t bytes) {
    uint8_t* p = wsp;
    wsp += (bytes + 255) & ~(size_t)255;
    return p;
  };
  float*    h    = (float*)alloc((size_t)BB * HH * 4);
  float*    gi   = (float*)alloc((size_t)BB * G3 * 4);
  float*    gh   = (float*)alloc((size_t)BB * G3 * 4);
  ushort_t* hhi  = (ushort_t*)alloc((size_t)BB * HH * 2);
  ushort_t* hlo  = (ushort_t*)alloc((size_t)BB * HH * 2);
  ushort_t* xh   = (ushort_t*)alloc((size_t)BB * DD * 2);
  ushort_t* xl   = (ushort_t*)alloc((size_t)BB * DD * 2);
  u64*      part = (u64*)alloc((size_t)BB * NBLK_LOG * 8);

  init_kernel<<<256, 256, 0, stream>>>(seq, emb, eos, h, hhi, hlo, xh, xl);

  for (int t = 0; t < T_STEPS; ++t) {
    float* lg = log_out + (size_t)t * BB * VV;
    gates_mfma<<<96, 256, 0, stream>>>(xh, xl, Wih, hhi, hlo, Whh, gi, gh);
    gru_gate<<<(BB * HH) / 256, 256, 0, stream>>>(gi, gh, bih, bhh, h, hhi, hlo);
    logits_mfma<<<NBLK_LOG, 256, 0, stream>>>(hhi, hlo, fcw, fcb, lg, part, t);
    finish_sample<<<BB, 256, 0, stream>>>(part, emb, idx_out + t * BB, xh, xl);
  }
}